// Round 17
// baseline (2225.108 us; speedup 1.0000x reference)
//
#include <hip/hip_runtime.h>
#include <hip/hip_bf16.h>
#include <cmath>

#define B_ 16
#define S_ 2048
#define D_ 512
#define L_ 4
#define FF_ 2048
#define V_ 33

typedef unsigned short u16;
typedef __attribute__((ext_vector_type(8))) short bf16x8;
typedef __attribute__((ext_vector_type(4))) float f32x4;

__device__ __forceinline__ u16 f2bf(float f) {
    unsigned x = __float_as_uint(f);
    unsigned r = (x + 0x7fffu + ((x >> 16) & 1u)) >> 16;
    return (u16)r;
}
__device__ __forceinline__ float bf2f(u16 u) { return __uint_as_float(((unsigned)u) << 16); }

__device__ __forceinline__ float wave_sum(float v) {
#pragma unroll
    for (int o = 32; o; o >>= 1) v += __shfl_xor(v, o);
    return v;
}

__device__ __forceinline__ void gload16(const u16* g, u16* l) {
    __builtin_amdgcn_global_load_lds((const __attribute__((address_space(1))) void*)g,
                                     (__attribute__((address_space(3))) void*)l, 16, 0, 0);
}

__device__ __forceinline__ uint4 pack8(const u16* ov) {
    uint4 p;
    p.x = (unsigned)ov[0] | ((unsigned)ov[1] << 16);
    p.y = (unsigned)ov[2] | ((unsigned)ov[3] << 16);
    p.z = (unsigned)ov[4] | ((unsigned)ov[5] << 16);
    p.w = (unsigned)ov[6] | ((unsigned)ov[7] << 16);
    return p;
}
__device__ __forceinline__ void unpack8(uint4 p, float* v) {
    v[0] = bf2f((u16)(p.x & 0xffff)); v[1] = bf2f((u16)(p.x >> 16));
    v[2] = bf2f((u16)(p.y & 0xffff)); v[3] = bf2f((u16)(p.y >> 16));
    v[4] = bf2f((u16)(p.z & 0xffff)); v[5] = bf2f((u16)(p.z >> 16));
    v[6] = bf2f((u16)(p.w & 0xffff)); v[7] = bf2f((u16)(p.w >> 16));
}

// ---------------- embedding (writes bf16 residual stream) ----------------
__global__ __launch_bounds__(256) void embed_kernel(
    const int* __restrict__ ids, const int* __restrict__ attr,
    const float* __restrict__ tok, const float* __restrict__ pos,
    const float* __restrict__ attre, u16* __restrict__ x)
{
    int idx = blockIdx.x * 256 + threadIdx.x;          // 8-elem group index
    const int total = B_ * S_ * (D_ / 8);
    if (idx >= total) return;
    int d8 = idx & (D_ / 8 - 1);
    int bs = idx >> 6;            // D_/8 = 64
    int s  = bs & (S_ - 1);
    int b  = bs >> 11;
    int id = ids[bs];
    int a  = attr[b];
    const float4* t4 = (const float4*)(tok   + (size_t)id * D_) + d8 * 2;
    const float4* p4 = (const float4*)(pos   + (size_t)s  * D_) + d8 * 2;
    const float4* a4 = (const float4*)(attre + (size_t)a  * D_) + d8 * 2;
    u16 ov[8];
#pragma unroll
    for (int h = 0; h < 2; h++) {
        float4 t = t4[h], p = p4[h], at = a4[h];
        ov[h * 4 + 0] = f2bf(t.x + p.x + at.x);
        ov[h * 4 + 1] = f2bf(t.y + p.y + at.y);
        ov[h * 4 + 2] = f2bf(t.z + p.z + at.z);
        ov[h * 4 + 3] = f2bf(t.w + p.w + at.w);
    }
    *(uint4*)(x + (size_t)idx * 8) = pack8(ov);
}

// ---- fused LN + transpose: h = LN(x), hT[z][d][s] = h  (per 64-row block) ----
#define LTS 66
__global__ __launch_bounds__(1024) void lnT_kernel(
    const u16* __restrict__ in, u16* __restrict__ h, u16* __restrict__ hT,
    const float* __restrict__ w, const float* __restrict__ b)
{
    __shared__ u16 tile[512 * LTS];    // 67584 B
    const int tid = threadIdx.x, lane = tid & 63, wv = tid >> 6;  // 16 waves
    const int rb = blockIdx.x;
    const int z  = rb >> 5;
    const int s0 = (rb & 31) * 64;

    float wv8[8], bv8[8];
#pragma unroll
    for (int k = 0; k < 8; k++) {
        wv8[k] = w[k * 64 + lane];
        bv8[k] = b[k * 64 + lane];
    }

#pragma unroll
    for (int i = 0; i < 4; i++) {
        const int rl = wv * 4 + i;
        const size_t grow = (size_t)rb * 64 + rl;
        const u16* xr = in + grow * D_;
        float xv[8];
#pragma unroll
        for (int k = 0; k < 8; k++) xv[k] = bf2f(xr[k * 64 + lane]);
        float s = 0.f;
#pragma unroll
        for (int k = 0; k < 8; k++) s += xv[k];
        s = wave_sum(s);
        float mu = s * (1.f / D_);
        float q = 0.f;
#pragma unroll
        for (int k = 0; k < 8; k++) { float d = xv[k] - mu; q += d * d; }
        q = wave_sum(q);
        float rs = rsqrtf(q * (1.f / D_) + 1e-5f);
        u16* hr = h + grow * D_;
#pragma unroll
        for (int k = 0; k < 8; k++) {
            u16 v = f2bf((xv[k] - mu) * rs * wv8[k] + bv8[k]);
            hr[k * 64 + lane] = v;
            tile[(k * 64 + lane) * LTS + rl] = v;
        }
    }
    __syncthreads();
    u16* hb = hT + (size_t)z * S_ * D_;
#pragma unroll
    for (int it = 0; it < 4; it++) {
        int idx = it * 1024 + tid;
        int d = idx >> 3, sg = (idx & 7) << 3;
        u16 v[8];
#pragma unroll
        for (int i = 0; i < 8; i++) v[i] = tile[d * LTS + sg + i];
        *(uint4*)(hb + (size_t)d * S_ + s0 + sg) = pack8(v);
    }
}

// ---------------- 64x64 transpose -> bf16, u32-packed both sides -------------
__device__ __forceinline__ void ld2(const float* p, int idx, u16& a, u16& b) {
    float2 v = ((const float2*)p)[idx];
    a = f2bf(v.x); b = f2bf(v.y);
}

__global__ void transpose64(const float* __restrict__ in, u16* __restrict__ out,
                            int R, int C, size_t sIn, size_t sOut)
{
    __shared__ u16 tile[64][66];
    const float* ip = in + (size_t)blockIdx.z * sIn;
    u16* op = out + (size_t)blockIdx.z * sOut;
    const int tx = threadIdx.x, ty = threadIdx.y;   // (32, 8)
#pragma unroll
    for (int i = 0; i < 8; i++) {
        int r = blockIdx.y * 64 + ty + i * 8;
        u16 a, b;
        ld2(ip + (size_t)r * C, blockIdx.x * 32 + tx, a, b);
        tile[tx * 2 + 0][ty + i * 8] = a;
        tile[tx * 2 + 1][ty + i * 8] = b;
    }
    __syncthreads();
#pragma unroll
    for (int i = 0; i < 8; i++) {
        int ocl = ty + i * 8;
        int oc  = blockIdx.x * 64 + ocl;
        unsigned w = (unsigned)tile[ocl][tx * 2] | ((unsigned)tile[ocl][tx * 2 + 1] << 16);
        ((unsigned*)(op + (size_t)oc * R + blockIdx.y * 64))[tx] = w;
    }
}

// ---------------- NT GEMM (PV / FF2 epilogues) ----------
// 128x128 tile, BK=64. T2 XOR-swizzle both-sides; conflicts = 0 (R5).
// T1: m204 bijective XCD remap (R7). E_PV: fused rowred prologue + divide.
enum { E_PV = 1, E_FF2 = 3 };

template <int EPI>
__global__ __launch_bounds__(256) void gemm_nt(
    const u16* __restrict__ A, size_t sAz, int lda,
    const u16* __restrict__ B, size_t sBz, int ldb,
    u16* Cb, size_t sCz, int ldc,
    int K,
    const u16* resid, size_t sRz,
    const float* __restrict__ bias,
    const float* __restrict__ aux, int b0)
{
    __shared__ __align__(16) u16 ldsA[128 * 64];
    __shared__ __align__(16) u16 ldsB[128 * 64];
    __shared__ float l2[EPI == E_PV ? 128 : 1][2];

    const int gx = gridDim.x, gy = gridDim.y;
    const int nwg = gx * gy * gridDim.z;
    int lid = blockIdx.x + gx * (blockIdx.y + gy * blockIdx.z);
    {
        const int q = nwg >> 3, r = nwg & 7;
        const int xcd = lid & 7, idx = lid >> 3;
        lid = (xcd < r ? xcd * (q + 1) : r * (q + 1) + (xcd - r) * q) + idx;
    }
    const int bx = lid % gx;
    const int t2 = lid / gx;
    const int by = t2 % gy;
    const int z  = t2 / gy;

    A += (size_t)z * sAz;
    B += (size_t)z * sBz;
    const size_t coff = (size_t)z * sCz;
    const int brow = by * 128, bcol = bx * 128;
    const int tid = threadIdx.x, lane = tid & 63, wid = tid >> 6;
    const int wr = wid >> 1, wc = wid & 1;

    if constexpr (EPI == E_PV) {
        const int nrows = b0;
        const int base = z * S_ + brow;
        const int r = tid >> 1, ih = (tid & 1) << 4;
        float s = 0.f;
#pragma unroll
        for (int i = 0; i < 16; i++)
            s += aux[(size_t)(ih + i) * nrows + base + r];
        l2[r][tid & 1] = s;
    }

    f32x4 acc[4][4];
#pragma unroll
    for (int m = 0; m < 4; m++)
#pragma unroll
        for (int n = 0; n < 4; n++) acc[m][n] = 0.0f;

    const int lg   = lane >> 3;
    const int srow = wid * 8 + lg;
    const int skk  = ((lane & 7) ^ lg) << 3;
    const int l15 = lane & 15, l7 = lane & 7, kh = lane >> 4;

    for (int k0 = 0; k0 < K; k0 += 64) {
        __syncthreads();
#pragma unroll
        for (int r = 0; r < 4; r++) {
            const u16* ga = A + (size_t)(brow + r * 32 + srow) * lda + (k0 + skk);
            const u16* gb = B + (size_t)(bcol + r * 32 + srow) * ldb + (k0 + skk);
            gload16(ga, &ldsA[r * 2048 + wid * 512]);
            gload16(gb, &ldsB[r * 2048 + wid * 512]);
        }
        __syncthreads();
#pragma unroll
        for (int kk = 0; kk < 64; kk += 32) {
            const int kc = (kk >> 3) + kh;
            const int kswz = ((kc ^ l7) << 3);
            bf16x8 af[4], bfv[4];
#pragma unroll
            for (int m = 0; m < 4; m++)
                af[m] = *(const bf16x8*)&ldsA[(wr * 64 + m * 16 + l15) * 64 + kswz];
#pragma unroll
            for (int n = 0; n < 4; n++)
                bfv[n] = *(const bf16x8*)&ldsB[(wc * 64 + n * 16 + l15) * 64 + kswz];
#pragma unroll
            for (int m = 0; m < 4; m++)
#pragma unroll
                for (int n = 0; n < 4; n++)
                    acc[m][n] = __builtin_amdgcn_mfma_f32_16x16x32_bf16(af[m], bfv[n], acc[m][n], 0, 0, 0);
        }
    }

#pragma unroll
    for (int m = 0; m < 4; m++)
#pragma unroll
        for (int n = 0; n < 4; n++) {
            int rowb = brow + wr * 64 + m * 16 + ((lane >> 4) << 2);
            int col  = bcol + wc * 64 + n * 16 + l15;
#pragma unroll
            for (int j = 0; j < 4; j++) {
                int row = rowb + j;
                float v = acc[m][n][j];
                size_t off = coff + (size_t)row * ldc + col;
                if constexpr (EPI == E_PV) {
                    int rl = row - brow;
                    float lv = l2[rl][0] + l2[rl][1];
                    Cb[off] = f2bf(v / lv +
                                   bf2f(resid[(size_t)z * sRz + (size_t)row * ldc + col]));
                } else {
                    Cb[off] = f2bf(v + bias[col] +
                                   bf2f(resid[(size_t)row * ldc + col]));
                }
            }
        }
}

// ---------------- FF1 with fused LN: t = gelu(LN(x) @ w1t + b1) --------------
// A-path: reg-staged LN (outproj-proven pattern) -> swizzled ds_write_b128
// (write-swz == read-swz, rule #21). Per row: 2 threads, stats via shfl_xor(1);
// var = E[x^2]-mu^2 (clamped) — fp32-rounding-level diff from two-pass form.
// ln_w/ln_b parked in LDS (pair-broadcast reads, conflict-free). B via gload16.
__global__ __launch_bounds__(256) void gemm_ff1(
    const u16* __restrict__ x, const u16* __restrict__ w1t,
    u16* __restrict__ tbuf, const float* __restrict__ bias,
    const float* __restrict__ lnw, const float* __restrict__ lnb)
{
    __shared__ __align__(16) u16 ldsA[128 * 64];
    __shared__ __align__(16) u16 ldsB[128 * 64];
    __shared__ float wln[512], bln[512];

    const int gx = gridDim.x, gy = gridDim.y;
    const int nwg = gx * gy;
    int lid = blockIdx.x + gx * blockIdx.y;
    {
        const int q = nwg >> 3, r = nwg & 7;
        const int xcd = lid & 7, idx = lid >> 3;
        lid = (xcd < r ? xcd * (q + 1) : r * (q + 1) + (xcd - r) * q) + idx;
    }
    const int bx = lid % gx;
    const int by = lid / gx;
    const int brow = by * 128, bcol = bx * 128;
    const int tid = threadIdx.x, lane = tid & 63, wid = tid >> 6;
    const int wr = wid >> 1, wc = wid & 1;

    // stage ln params into LDS
    if (tid < 128) {
        float4 wv = ((const float4*)lnw)[tid];
        float4 bv = ((const float4*)lnb)[tid];
        *(float4*)&wln[tid * 4] = wv;
        *(float4*)&bln[tid * 4] = bv;
    }

    // per-row LN stats: thread (ar, half) covers cols {k0 + half*32 .. +31}
    const int ar = tid >> 1, ah = (tid & 1) * 32;
    const u16* xrow = x + (size_t)(brow + ar) * D_;
    float sum = 0.f, sq = 0.f;
#pragma unroll
    for (int k0 = 0; k0 < 512; k0 += 64) {
#pragma unroll
        for (int j = 0; j < 4; j++) {
            float v[8];
            unpack8(*(const uint4*)(xrow + k0 + ah + j * 8), v);
#pragma unroll
            for (int e = 0; e < 8; e++) { sum += v[e]; sq += v[e] * v[e]; }
        }
    }
    sum += __shfl_xor(sum, 1);
    sq  += __shfl_xor(sq, 1);
    const float mu = sum * (1.f / D_);
    const float var = fmaxf(sq * (1.f / D_) - mu * mu, 0.f);
    const float rs = rsqrtf(var + 1e-5f);

    f32x4 acc[4][4];
#pragma unroll
    for (int m = 0; m < 4; m++)
#pragma unroll
        for (int n = 0; n < 4; n++) acc[m][n] = 0.0f;

    const int lg   = lane >> 3;
    const int srow = wid * 8 + lg;
    const int skk  = ((lane & 7) ^ lg) << 3;
    const int l15 = lane & 15, l7 = lane & 7, kh = lane >> 4;
    const int a7 = ar & 7;

    for (int k0 = 0; k0 < 512; k0 += 64) {
        __syncthreads();
#pragma unroll
        for (int r = 0; r < 4; r++)
            gload16(w1t + (size_t)(bcol + r * 32 + srow) * D_ + (k0 + skk),
                    &ldsB[r * 2048 + wid * 512]);
        // A: read x, normalize, swizzled ds_write
#pragma unroll
        for (int j = 0; j < 4; j++) {
            float v[8];
            unpack8(*(const uint4*)(xrow + k0 + ah + j * 8), v);
            u16 t[8];
#pragma unroll
            for (int e = 0; e < 8; e++) {
                int c = k0 + ah + j * 8 + e;
                t[e] = f2bf((v[e] - mu) * rs * wln[c] + bln[c]);
            }
            int kc = (ah >> 3) + j;
            *(uint4*)&ldsA[ar * 64 + ((kc ^ a7) << 3)] = pack8(t);
        }
        __syncthreads();
#pragma unroll
        for (int kk = 0; kk < 64; kk += 32) {
            const int kc = (kk >> 3) + kh;
            const int kswz = ((kc ^ l7) << 3);
            bf16x8 af[4], bfv[4];
#pragma unroll
            for (int m = 0; m < 4; m++)
                af[m] = *(const bf16x8*)&ldsA[(wr * 64 + m * 16 + l15) * 64 + kswz];
#pragma unroll
            for (int n = 0; n < 4; n++)
                bfv[n] = *(const bf16x8*)&ldsB[(wc * 64 + n * 16 + l15) * 64 + kswz];
#pragma unroll
            for (int m = 0; m < 4; m++)
#pragma unroll
                for (int n = 0; n < 4; n++)
                    acc[m][n] = __builtin_amdgcn_mfma_f32_16x16x32_bf16(af[m], bfv[n], acc[m][n], 0, 0, 0);
        }
    }

#pragma unroll
    for (int m = 0; m < 4; m++)
#pragma unroll
        for (int n = 0; n < 4; n++) {
            int rowb = brow + wr * 64 + m * 16 + ((lane >> 4) << 2);
            int col  = bcol + wc * 64 + n * 16 + l15;
#pragma unroll
            for (int j = 0; j < 4; j++) {
                float t = acc[m][n][j] + bias[col];
                tbuf[(size_t)(rowb + j) * FF_ + col] =
                    f2bf(0.5f * t * (1.f + erff(t * 0.70710678118f)));
            }
        }
}

// ---------------- SC GEMM with symmetry halving (verified R15) ---------------
__global__ __launch_bounds__(256) void gemm_sc(
    const u16* __restrict__ h, u16* __restrict__ P,
    const float* __restrict__ mask, int b0, float scale,
    float* __restrict__ psum, int nbatch)
{
    __shared__ __align__(16) u16 ldsbuf[2][128 * 64];
    u16* ldsA = ldsbuf[0];
    u16* ldsB = ldsbuf[1];
    u16* mt   = &ldsbuf[0][0];          // union: [64][136] mirror staging tile

    const int nwg = 136 * nbatch;
    int lid = blockIdx.x + 136 * blockIdx.z;
    {
        const int q = nwg >> 3, r = nwg & 7;
        const int xcd = lid & 7, idx = lid >> 3;
        lid = (xcd < r ? xcd * (q + 1) : r * (q + 1) + (xcd - r) * q) + idx;
    }
    int t = lid % 136;
    const int z = lid / 136;
    int by = 0;
#pragma unroll 1
    while (t >= 16 - by) { t -= 16 - by; by++; }
    const int bx = by + t;

    const u16* A = h + (size_t)z * S_ * D_;
    const size_t coff = (size_t)z * S_ * S_;
    const int brow = by * 128, bcol = bx * 128;
    const int tid = threadIdx.x, lane = tid & 63, wid = tid >> 6;
    const int wr = wid >> 1, wc = wid & 1;

    f32x4 acc[4][4];
#pragma unroll
    for (int m = 0; m < 4; m++)
#pragma unroll
        for (int n = 0; n < 4; n++) acc[m][n] = 0.0f;

    const int lg   = lane >> 3;
    const int srow = wid * 8 + lg;
    const int skk  = ((lane & 7) ^ lg) << 3;
    const int l15 = lane & 15, l7 = lane & 7, kh = lane >> 4;

    for (int k0 = 0; k0 < D_; k0 += 64) {
        __syncthreads();
#pragma unroll
        for (int r = 0; r < 4; r++) {
            const u16* ga = A + (size_t)(brow + r * 32 + srow) * D_ + (k0 + skk);
            const u16* gb = A + (size_t)(bcol + r * 32 + srow) * D_ + (k0 + skk);
            gload16(ga, &ldsA[r * 2048 + wid * 512]);
            gload16(gb, &ldsB[r * 2048 + wid * 512]);
        }
        __syncthreads();
#pragma unroll
        for (int kk = 0; kk < 64; kk += 32) {
            const int kc = (kk >> 3) + kh;
            const int kswz = ((kc ^ l7) << 3);
            bf16x8 af[4], bfv[4];
#pragma unroll
            for (int m = 0; m < 4; m++)
                af[m] = *(const bf16x8*)&ldsA[(wr * 64 + m * 16 + l15) * 64 + kswz];
#pragma unroll
            for (int n = 0; n < 4; n++)
                bfv[n] = *(const bf16x8*)&ldsB[(wc * 64 + n * 16 + l15) * 64 + kswz];
#pragma unroll
            for (int m = 0; m < 4; m++)
#pragma unroll
                for (int n = 0; n < 4; n++)
                    acc[m][n] = __builtin_amdgcn_mfma_f32_16x16x32_bf16(af[m], bfv[n], acc[m][n], 0, 0, 0);
        }
    }

    const float* mrow = mask + (size_t)(b0 + z) * S_;
    const int nrows = nbatch * S_;

    float rsum[4][4];
#pragma unroll
    for (int m = 0; m < 4; m++)
#pragma unroll
        for (int j = 0; j < 4; j++) rsum[m][j] = 0.f;

#pragma unroll
    for (int m = 0; m < 4; m++)
#pragma unroll
        for (int n = 0; n < 4; n++) {
            int rowb = brow + wr * 64 + m * 16 + (kh << 2);
            int col  = bcol + wc * 64 + n * 16 + l15;
            float madd_c = (1.f - mrow[col]) * -1e9f;
#pragma unroll
            for (int j = 0; j < 4; j++) {
                int row = rowb + j;
                float ev = __expf(acc[m][n][j] * scale + madd_c);
                P[coff + (size_t)row * S_ + col] = f2bf(ev);
                rsum[m][j] += ev;
            }
        }
#pragma unroll
    for (int m = 0; m < 4; m++) {
        int rowl = brow + wr * 64 + m * 16 + (kh << 2);
#pragma unroll
        for (int j = 0; j < 4; j++) {
            float s = rsum[m][j];
            s += __shfl_xor(s, 1);
            s += __shfl_xor(s, 2);
            s += __shfl_xor(s, 4);
            s += __shfl_xor(s, 8);
            if (l15 == 0)
                psum[(size_t)(bx * 2 + wc) * nrows + (size_t)z * S_ + rowl + j] = s;
        }
    }

    if (bx != by) {
#pragma unroll 1
        for (int rnd = 0; rnd < 2; rnd++) {
            __syncthreads();
            if (wc == rnd) {
#pragma unroll
                for (int n = 0; n < 4; n++) {
                    float csum = 0.f;
                    const int mrow_l = n * 16 + l15;
#pragma unroll
                    for (int m = 0; m < 4; m++) {
                        const int lr = wr * 64 + m * 16 + (kh << 2);
                        u16 e2[4];
#pragma unroll
                        for (int j = 0; j < 4; j++) {
                            float madd_r = (1.f - mrow[brow + lr + j]) * -1e9f;
                            float em = __expf(acc[m][n][j] * scale + madd_r);
                            csum += em;
                            e2[j] = f2bf(em);
                        }
                        unsigned* m32 = (unsigned*)&mt[mrow_l * 136 + lr];
                        m32[0] = (unsigned)e2[0] | ((unsigned)e2[1] << 16);
                        m32[1] = (unsigned)e2[2] | ((unsigned)e2[3] << 16);
                    }
                    csum += __shfl_xor(csum, 16);
                    csum += __shfl_xor(csum, 32);
                    if (lane < 16)
                        psum[(size_t)(by * 2 + wr) * nrows + (size_t)z * S_ +
                             bcol + rnd * 64 + n * 16 + lane] = csum;
                }
            }
            __syncthreads();
#pragma unroll 1
            for (int i = tid; i < 64 * 16; i += 256) {
                int rr = i >> 4, c16 = (i & 15) << 3;
                u16 v[8];
#pragma unroll
                for (int q = 0; q < 8; q++) v[q] = mt[rr * 136 + c16 + q];
                *(uint4*)(P + coff + (size_t)(bcol + rnd * 64 + rr) * S_ + brow + c16) = pack8(v);
            }
        }
    }
}

// ---------------- out_w pad+transpose: WTb[64][512] bf16 ----------------
__global__ __launch_bounds__(256) void wtb_kernel(
    const float* __restrict__ W, u16* __restrict__ WTb)
{
    int i = blockIdx.x * 256 + threadIdx.x;
    if (i >= 64 * 512) return;
    int n = i >> 9, k = i & 511;
    WTb[i] = f2bf(n < V_ ? W[k * V_ + n] : 0.f);
}

// ---------------- output projection via MFMA: out = x(bf16) @ W + b ----------
__global__ __launch_bounds__(256) void outproj_mfma(
    const u16* __restrict__ x, const u16* __restrict__ WTb,
    const float* __restrict__ bias, float* __restrict__ out)
{
    __shared__ __align__(16) u16 ldsA[128 * 64];
    __shared__ __align__(16) u16 ldsB[64 * 64];
    __shared__ float obuf[128][34];
    const int brow = blockIdx.x * 128;
    const int tid = threadIdx.x, lane = tid & 63, wid = tid >> 6;
    const int wr = wid >> 1, wc = wid & 1;
    const int l15 = lane & 15, l7 = lane & 7, kh = lane >> 4;
    const int lg = lane >> 3, srow = wid * 8 + lg;
    const int skk = ((lane & 7) ^ lg) << 3;

    f32x4 acc[4][2];
#pragma unroll
    for (int m = 0; m < 4; m++)
#pragma unroll
        for (int n = 0; n < 2; n++) acc[m][n] = 0.0f;

    for (int k0 = 0; k0 < 512; k0 += 64) {
        __syncthreads();
#pragma unroll
        for (int r = 0; r < 2; r++)
            gload16(WTb + (size_t)(r * 32 + srow) * 512 + (k0 + skk),
                    &ldsB[r * 2048 + wid * 512]);
#pragma unroll
        for (int r = 0; r < 4; r++)
            gload16(x + (size_t)(brow + r * 32 + srow) * 512 + (k0 + skk),
                    &ldsA[r * 2048 + wid * 512]);
        __syncthreads();
#pragma unroll
        for (int kk = 0; kk < 64; kk += 32) {
            const int kc = (kk >> 3) + kh;
            const int kswz = ((kc ^ l7) << 3);
            bf16x8 af[4], bfv[2];
#pragma unroll
            for (int m = 0; m < 4; m++)
                af[m] = *(const bf16x8*)&ldsA[(wr * 64 + m * 16 + l15) * 64 + kswz];
#pragma unroll
            for (int n = 0; n < 2; n++)
                bfv[n] = *(const bf16x8*)&ldsB[(wc * 32 + n * 16 + l15) * 64 + kswz];
#pragma unroll
            for (int m = 0; m < 4; m++)
#pragma unroll
                for (int n = 0; n < 2; n++)
                    acc[m][n] = __builtin_amdgcn_mfma_f32_16x16x32_bf16(af[m], bfv[n], acc[m][n], 0, 0, 0);
        }
    }

#pragma unroll
    for (int m = 0; m < 4; m++)
#pragma unroll
        for (int n = 0; n < 2; n++) {
            int rowl = wr * 64 + m * 16 + ((lane >> 4) << 2);
            int col  = wc * 32 + n * 16 + l15;
            if (col < V_) {
#pragma unroll
                for (int j = 0; j < 4; j++)
                    obuf[rowl + j][col] = acc[m][n][j] + bias[col];
            }
        }
    __syncthreads();
    float* ob = out + (size_t)brow * V_;
#pragma unroll 1
    for (int i = tid; i < 128 * V_; i += 256)
        ob[i] = obuf[i / V_][i % V_];
}

extern "C" void kernel_launch(void* const* d_in, const int* in_sizes, int n_in,
                              void* d_out, int out_size, void* d_ws, size_t ws_size,
                              hipStream_t stream)
{
    const int*   input_ids = (const int*)d_in[0];
    const int*   comb      = (const int*)d_in[1];
    const float* amask     = (const float*)d_in[2];
    const float* tok       = (const float*)d_in[3];
    const float* pos       = (const float*)d_in[4];
    const float* attre     = (const float*)d_in[5];
    const float* ln_w      = (const float*)d_in[6];
    const float* ln_b      = (const float*)d_in[7];
    const float* w1        = (const float*)d_in[8];
    const float* b1        = (const float*)d_in[9];
    const float* w2        = (const float*)d_in[10];
    const float* b2        = (const float*)d_in[11];
    const float* out_w     = (const float*)d_in[12];
    const float* out_b     = (const float*)d_in[13];
    float* out = (float*)d_out;
    (void)in_sizes; (void)n_in; (void)out_size;

    // ---- adaptive workspace tiers (ws_size-aware; deterministic) ----
    int NB_A, RC;
    if      (ws_size >= 300000000ULL) { NB_A = 16; RC = 32768; }
    else if (ws_size >= 180000000ULL) { NB_A = 8;  RC = 16384; }
    else if (ws_size >= 120000000ULL) { NB_A = 4;  RC = 8192;  }
    else                              { NB_A = 2;  RC = 4096;  }
    const int HR = NB_A * S_;

    unsigned char* ws = (unsigned char*)d_ws;
    size_t off = 0;
    auto carve = [&](size_t bytes) {
        void* p = ws + off;
        off += (bytes + 255) & ~(size_t)255;
        return p;
    };
    u16* x      = (u16*)carve((size_t)B_ * S_ * D_ * 2);          // bf16 residual
    u16* w1t    = (u16*)carve((size_t)L_ * D_ * FF_ * 2);
    u16* w2t    = (u16*)carve((size_t)L_ * D_ * FF_ * 2);
    u16* h      = (u16*)carve((size_t)HR * D_ * 2);
    u16* hT     = (u16*)carve((size_t)NB_A * S_ * D_ * 2);
    float* psum = (float*)carve((size_t)NB_A * S_ * 32 * 4);
    u16* WTb    = (u16*)carve((size_t)64 * 512 * 2);
    size_t scP_bytes  = (size_t)NB_A * S_ * S_ * 2;
    size_t tbuf_bytes = (size_t)RC * FF_ * 2;
    void* un = carve(scP_bytes > tbuf_bytes ? scP_bytes : tbuf_bytes);
    u16* scP  = (u16*)un;
    u16* tbuf = (u16*)un;

    const float scl = 1.0f / sqrtf((float)D_);
    const int nG = B_ / NB_A;
    const int nC = (B_ * S_) / RC;

    embed_kernel<<<(B_ * S_ * (D_ / 8)) / 256, 256, 0, stream>>>(input_ids, comb, tok, pos, attre, x);
    transpose64<<<dim3(FF_ / 64, D_ / 64, L_), dim3(32, 8), 0, stream>>>(
        w1, w1t, D_, FF_, (size_t)D_ * FF_, (size_t)FF_ * D_);
    transpose64<<<dim3(D_ / 64, FF_ / 64, L_), dim3(32, 8), 0, stream>>>(
        w2, w2t, FF_, D_, (size_t)FF_ * D_, (size_t)D_ * FF_);
    wtb_kernel<<<128, 256, 0, stream>>>(out_w, WTb);

    for (int l = 0; l < L_; l++) {
        const float* lw = ln_w + l * D_;
        const float* lb = ln_b + l * D_;

        for (int g = 0; g < nG; g++) {
            u16* xg = x + (size_t)g * NB_A * S_ * D_;
            lnT_kernel<<<(NB_A * S_) / 64, 1024, 0, stream>>>(xg, h, hT, lw, lb);
            gemm_sc<<<dim3(136, 1, NB_A), 256, 0, stream>>>(
                h, scP, amask, g * NB_A, scl, psum, NB_A);
            gemm_nt<E_PV><<<dim3(D_ / 128, S_ / 128, NB_A), 256, 0, stream>>>(
                scP, (size_t)S_ * S_, S_,
                hT, (size_t)S_ * D_, S_,
                xg, (size_t)S_ * D_, D_,
                S_, xg, (size_t)S_ * D_, nullptr, psum, NB_A * S_);
        }

        for (int c = 0; c < nC; c++) {
            size_t roff = (size_t)c * RC;
            // t = gelu(LN(x) @ w1 + b1)  -- LN fused into A-staging
            gemm_ff1<<<dim3(FF_ / 128, RC / 128), 256, 0, stream>>>(
                x + roff * D_, w1t + (size_t)l * FF_ * D_,
                tbuf, b1 + l * FF_, lw, lb);
            gemm_nt<E_FF2><<<dim3(D_ / 128, RC / 128, 1), 256, 0, stream>>>(
                tbuf, 0, FF_,
                w2t + (size_t)l * D_ * FF_, 0, FF_,
                x + roff * D_, 0, D_,
                FF_, x + roff * D_, 0, b2 + l * D_, nullptr, 0);
        }
    }

    outproj_mfma<<<(B_ * S_) / 128, 256, 0, stream>>>(x, WTb, out_b, out);
}

// Round 18
// 1904.620 us; speedup vs baseline: 1.1683x; 1.1683x over previous
//
#include <hip/hip_runtime.h>
#include <hip/hip_bf16.h>
#include <cmath>

#define B_ 16
#define S_ 2048
#define D_ 512
#define L_ 4
#define FF_ 2048
#define V_ 33

typedef unsigned short u16;
typedef __attribute__((ext_vector_type(8))) short bf16x8;
typedef __attribute__((ext_vector_type(4))) float f32x4;

__device__ __forceinline__ u16 f2bf(float f) {
    unsigned x = __float_as_uint(f);
    unsigned r = (x + 0x7fffu + ((x >> 16) & 1u)) >> 16;
    return (u16)r;
}
__device__ __forceinline__ float bf2f(u16 u) { return __uint_as_float(((unsigned)u) << 16); }

__device__ __forceinline__ float wave_sum(float v) {
#pragma unroll
    for (int o = 32; o; o >>= 1) v += __shfl_xor(v, o);
    return v;
}

__device__ __forceinline__ void gload16(const u16* g, u16* l) {
    __builtin_amdgcn_global_load_lds((const __attribute__((address_space(1))) void*)g,
                                     (__attribute__((address_space(3))) void*)l, 16, 0, 0);
}

__device__ __forceinline__ uint4 pack8(const u16* ov) {
    uint4 p;
    p.x = (unsigned)ov[0] | ((unsigned)ov[1] << 16);
    p.y = (unsigned)ov[2] | ((unsigned)ov[3] << 16);
    p.z = (unsigned)ov[4] | ((unsigned)ov[5] << 16);
    p.w = (unsigned)ov[6] | ((unsigned)ov[7] << 16);
    return p;
}

// ---------------- embedding (writes bf16 residual stream) ----------------
__global__ __launch_bounds__(256) void embed_kernel(
    const int* __restrict__ ids, const int* __restrict__ attr,
    const float* __restrict__ tok, const float* __restrict__ pos,
    const float* __restrict__ attre, u16* __restrict__ x)
{
    int idx = blockIdx.x * 256 + threadIdx.x;          // 8-elem group index
    const int total = B_ * S_ * (D_ / 8);
    if (idx >= total) return;
    int d8 = idx & (D_ / 8 - 1);
    int bs = idx >> 6;            // D_/8 = 64
    int s  = bs & (S_ - 1);
    int b  = bs >> 11;
    int id = ids[bs];
    int a  = attr[b];
    const float4* t4 = (const float4*)(tok   + (size_t)id * D_) + d8 * 2;
    const float4* p4 = (const float4*)(pos   + (size_t)s  * D_) + d8 * 2;
    const float4* a4 = (const float4*)(attre + (size_t)a  * D_) + d8 * 2;
    u16 ov[8];
#pragma unroll
    for (int h = 0; h < 2; h++) {
        float4 t = t4[h], p = p4[h], at = a4[h];
        ov[h * 4 + 0] = f2bf(t.x + p.x + at.x);
        ov[h * 4 + 1] = f2bf(t.y + p.y + at.y);
        ov[h * 4 + 2] = f2bf(t.z + p.z + at.z);
        ov[h * 4 + 3] = f2bf(t.w + p.w + at.w);
    }
    *(uint4*)(x + (size_t)idx * 8) = pack8(ov);
}

// ---------------- layernorm (bf16 in -> bf16 out) ----------------
__global__ __launch_bounds__(256) void ln_kernel(
    const u16* __restrict__ in, u16* __restrict__ out,
    const float* __restrict__ w, const float* __restrict__ b, int rows)
{
    int gw = (int)((blockIdx.x * 256 + threadIdx.x) >> 6);
    int lane = threadIdx.x & 63;
    if (gw >= rows) return;
    uint4 pk = *(const uint4*)(in + (size_t)gw * D_ + lane * 8);
    float xv[8];
    xv[0] = bf2f((u16)(pk.x & 0xffff)); xv[1] = bf2f((u16)(pk.x >> 16));
    xv[2] = bf2f((u16)(pk.y & 0xffff)); xv[3] = bf2f((u16)(pk.y >> 16));
    xv[4] = bf2f((u16)(pk.z & 0xffff)); xv[5] = bf2f((u16)(pk.z >> 16));
    xv[6] = bf2f((u16)(pk.w & 0xffff)); xv[7] = bf2f((u16)(pk.w >> 16));
    float s = 0.f;
#pragma unroll
    for (int k = 0; k < 8; k++) s += xv[k];
    s = wave_sum(s);
    float mu = s * (1.f / D_);
    float q = 0.f;
#pragma unroll
    for (int k = 0; k < 8; k++) { float d = xv[k] - mu; q += d * d; }
    q = wave_sum(q);
    float rs = rsqrtf(q * (1.f / D_) + 1e-5f);
    const float4* w4 = (const float4*)w;
    const float4* b4 = (const float4*)b;
    float4 w0 = w4[lane * 2], w1v = w4[lane * 2 + 1];
    float4 b0 = b4[lane * 2], b1v = b4[lane * 2 + 1];
    float wv[8] = {w0.x, w0.y, w0.z, w0.w, w1v.x, w1v.y, w1v.z, w1v.w};
    float bv[8] = {b0.x, b0.y, b0.z, b0.w, b1v.x, b1v.y, b1v.z, b1v.w};
    u16 ov[8];
#pragma unroll
    for (int k = 0; k < 8; k++) ov[k] = f2bf((xv[k] - mu) * rs * wv[k] + bv[k]);
    *(uint4*)(out + (size_t)gw * D_ + lane * 8) = pack8(ov);
}

// ---- fused LN + transpose: h = LN(x), hT[z][d][s] = h  (per 64-row block) ----
#define LTS 66
__global__ __launch_bounds__(1024) void lnT_kernel(
    const u16* __restrict__ in, u16* __restrict__ h, u16* __restrict__ hT,
    const float* __restrict__ w, const float* __restrict__ b)
{
    __shared__ u16 tile[512 * LTS];    // 67584 B
    const int tid = threadIdx.x, lane = tid & 63, wv = tid >> 6;  // 16 waves
    const int rb = blockIdx.x;
    const int z  = rb >> 5;
    const int s0 = (rb & 31) * 64;

    float wv8[8], bv8[8];
#pragma unroll
    for (int k = 0; k < 8; k++) {
        wv8[k] = w[k * 64 + lane];
        bv8[k] = b[k * 64 + lane];
    }

#pragma unroll
    for (int i = 0; i < 4; i++) {
        const int rl = wv * 4 + i;
        const size_t grow = (size_t)rb * 64 + rl;
        const u16* xr = in + grow * D_;
        float xv[8];
#pragma unroll
        for (int k = 0; k < 8; k++) xv[k] = bf2f(xr[k * 64 + lane]);
        float s = 0.f;
#pragma unroll
        for (int k = 0; k < 8; k++) s += xv[k];
        s = wave_sum(s);
        float mu = s * (1.f / D_);
        float q = 0.f;
#pragma unroll
        for (int k = 0; k < 8; k++) { float d = xv[k] - mu; q += d * d; }
        q = wave_sum(q);
        float rs = rsqrtf(q * (1.f / D_) + 1e-5f);
        u16* hr = h + grow * D_;
#pragma unroll
        for (int k = 0; k < 8; k++) {
            u16 v = f2bf((xv[k] - mu) * rs * wv8[k] + bv8[k]);
            hr[k * 64 + lane] = v;
            tile[(k * 64 + lane) * LTS + rl] = v;
        }
    }
    __syncthreads();
    u16* hb = hT + (size_t)z * S_ * D_;
#pragma unroll
    for (int it = 0; it < 4; it++) {
        int idx = it * 1024 + tid;
        int d = idx >> 3, sg = (idx & 7) << 3;
        u16 v[8];
#pragma unroll
        for (int i = 0; i < 8; i++) v[i] = tile[d * LTS + sg + i];
        *(uint4*)(hb + (size_t)d * S_ + s0 + sg) = pack8(v);
    }
}

// ---------------- 64x64 transpose -> bf16, u32-packed both sides -------------
__device__ __forceinline__ void ld2(const float* p, int idx, u16& a, u16& b) {
    float2 v = ((const float2*)p)[idx];
    a = f2bf(v.x); b = f2bf(v.y);
}

__global__ void transpose64(const float* __restrict__ in, u16* __restrict__ out,
                            int R, int C, size_t sIn, size_t sOut)
{
    __shared__ u16 tile[64][66];
    const float* ip = in + (size_t)blockIdx.z * sIn;
    u16* op = out + (size_t)blockIdx.z * sOut;
    const int tx = threadIdx.x, ty = threadIdx.y;   // (32, 8)
#pragma unroll
    for (int i = 0; i < 8; i++) {
        int r = blockIdx.y * 64 + ty + i * 8;
        u16 a, b;
        ld2(ip + (size_t)r * C, blockIdx.x * 32 + tx, a, b);
        tile[tx * 2 + 0][ty + i * 8] = a;
        tile[tx * 2 + 1][ty + i * 8] = b;
    }
    __syncthreads();
#pragma unroll
    for (int i = 0; i < 8; i++) {
        int ocl = ty + i * 8;
        int oc  = blockIdx.x * 64 + ocl;
        unsigned w = (unsigned)tile[ocl][tx * 2] | ((unsigned)tile[ocl][tx * 2 + 1] << 16);
        ((unsigned*)(op + (size_t)oc * R + blockIdx.y * 64))[tx] = w;
    }
}

// ---------------- NT GEMM (PV / GELU / FF2 epilogues) ----------
// 128x128 tile, BK=64. T2 XOR-swizzle both-sides; conflicts = 0 (R5).
// T1: m204 bijective XCD remap (R7). E_PV: fused rowred prologue + divide.
// R17 note: LN-fused-into-FF1 REGRESSED (119us vs 85us: LN row-pass replicated
// 16x by col-blocks + lost gload_lds). Separate ln_kernel is the right split.
enum { E_PV = 1, E_GELU = 2, E_FF2 = 3 };

template <int EPI>
__global__ __launch_bounds__(256) void gemm_nt(
    const u16* __restrict__ A, size_t sAz, int lda,
    const u16* __restrict__ B, size_t sBz, int ldb,
    u16* Cb, size_t sCz, int ldc,
    int K,
    const u16* resid, size_t sRz,
    const float* __restrict__ bias,
    const float* __restrict__ aux, int b0)
{
    __shared__ __align__(16) u16 ldsA[128 * 64];
    __shared__ __align__(16) u16 ldsB[128 * 64];
    __shared__ float l2[EPI == E_PV ? 128 : 1][2];

    const int gx = gridDim.x, gy = gridDim.y;
    const int nwg = gx * gy * gridDim.z;
    int lid = blockIdx.x + gx * (blockIdx.y + gy * blockIdx.z);
    {
        const int q = nwg >> 3, r = nwg & 7;
        const int xcd = lid & 7, idx = lid >> 3;
        lid = (xcd < r ? xcd * (q + 1) : r * (q + 1) + (xcd - r) * q) + idx;
    }
    const int bx = lid % gx;
    const int t2 = lid / gx;
    const int by = t2 % gy;
    const int z  = t2 / gy;

    A += (size_t)z * sAz;
    B += (size_t)z * sBz;
    const size_t coff = (size_t)z * sCz;
    const int brow = by * 128, bcol = bx * 128;
    const int tid = threadIdx.x, lane = tid & 63, wid = tid >> 6;
    const int wr = wid >> 1, wc = wid & 1;

    if constexpr (EPI == E_PV) {
        const int nrows = b0;
        const int base = z * S_ + brow;
        const int r = tid >> 1, ih = (tid & 1) << 4;
        float s = 0.f;
#pragma unroll
        for (int i = 0; i < 16; i++)
            s += aux[(size_t)(ih + i) * nrows + base + r];
        l2[r][tid & 1] = s;
    }

    f32x4 acc[4][4];
#pragma unroll
    for (int m = 0; m < 4; m++)
#pragma unroll
        for (int n = 0; n < 4; n++) acc[m][n] = 0.0f;

    const int lg   = lane >> 3;
    const int srow = wid * 8 + lg;
    const int skk  = ((lane & 7) ^ lg) << 3;
    const int l15 = lane & 15, l7 = lane & 7, kh = lane >> 4;

    for (int k0 = 0; k0 < K; k0 += 64) {
        __syncthreads();
#pragma unroll
        for (int r = 0; r < 4; r++) {
            const u16* ga = A + (size_t)(brow + r * 32 + srow) * lda + (k0 + skk);
            const u16* gb = B + (size_t)(bcol + r * 32 + srow) * ldb + (k0 + skk);
            gload16(ga, &ldsA[r * 2048 + wid * 512]);
            gload16(gb, &ldsB[r * 2048 + wid * 512]);
        }
        __syncthreads();
#pragma unroll
        for (int kk = 0; kk < 64; kk += 32) {
            const int kc = (kk >> 3) + kh;
            const int kswz = ((kc ^ l7) << 3);
            bf16x8 af[4], bfv[4];
#pragma unroll
            for (int m = 0; m < 4; m++)
                af[m] = *(const bf16x8*)&ldsA[(wr * 64 + m * 16 + l15) * 64 + kswz];
#pragma unroll
            for (int n = 0; n < 4; n++)
                bfv[n] = *(const bf16x8*)&ldsB[(wc * 64 + n * 16 + l15) * 64 + kswz];
#pragma unroll
            for (int m = 0; m < 4; m++)
#pragma unroll
                for (int n = 0; n < 4; n++)
                    acc[m][n] = __builtin_amdgcn_mfma_f32_16x16x32_bf16(af[m], bfv[n], acc[m][n], 0, 0, 0);
        }
    }

#pragma unroll
    for (int m = 0; m < 4; m++)
#pragma unroll
        for (int n = 0; n < 4; n++) {
            int rowb = brow + wr * 64 + m * 16 + ((lane >> 4) << 2);
            int col  = bcol + wc * 64 + n * 16 + l15;
#pragma unroll
            for (int j = 0; j < 4; j++) {
                int row = rowb + j;
                float v = acc[m][n][j];
                size_t off = coff + (size_t)row * ldc + col;
                if constexpr (EPI == E_PV) {
                    int rl = row - brow;
                    float lv = l2[rl][0] + l2[rl][1];
                    Cb[off] = f2bf(v / lv +
                                   bf2f(resid[(size_t)z * sRz + (size_t)row * ldc + col]));
                } else if constexpr (EPI == E_GELU) {
                    float t = v + bias[col];
                    Cb[off] = f2bf(0.5f * t * (1.f + erff(t * 0.70710678118f)));
                } else {
                    Cb[off] = f2bf(v + bias[col] +
                                   bf2f(resid[(size_t)row * ldc + col]));
                }
            }
        }
}

// ---------------- SC GEMM with symmetry halving (verified R15) ---------------
__global__ __launch_bounds__(256) void gemm_sc(
    const u16* __restrict__ h, u16* __restrict__ P,
    const float* __restrict__ mask, int b0, float scale,
    float* __restrict__ psum, int nbatch)
{
    __shared__ __align__(16) u16 ldsbuf[2][128 * 64];
    u16* ldsA = ldsbuf[0];
    u16* ldsB = ldsbuf[1];
    u16* mt   = &ldsbuf[0][0];          // union: [64][136] mirror staging tile

    const int nwg = 136 * nbatch;
    int lid = blockIdx.x + 136 * blockIdx.z;
    {
        const int q = nwg >> 3, r = nwg & 7;
        const int xcd = lid & 7, idx = lid >> 3;
        lid = (xcd < r ? xcd * (q + 1) : r * (q + 1) + (xcd - r) * q) + idx;
    }
    int t = lid % 136;
    const int z = lid / 136;
    int by = 0;
#pragma unroll 1
    while (t >= 16 - by) { t -= 16 - by; by++; }
    const int bx = by + t;

    const u16* A = h + (size_t)z * S_ * D_;
    const size_t coff = (size_t)z * S_ * S_;
    const int brow = by * 128, bcol = bx * 128;
    const int tid = threadIdx.x, lane = tid & 63, wid = tid >> 6;
    const int wr = wid >> 1, wc = wid & 1;

    f32x4 acc[4][4];
#pragma unroll
    for (int m = 0; m < 4; m++)
#pragma unroll
        for (int n = 0; n < 4; n++) acc[m][n] = 0.0f;

    const int lg   = lane >> 3;
    const int srow = wid * 8 + lg;
    const int skk  = ((lane & 7) ^ lg) << 3;
    const int l15 = lane & 15, l7 = lane & 7, kh = lane >> 4;

    for (int k0 = 0; k0 < D_; k0 += 64) {
        __syncthreads();
#pragma unroll
        for (int r = 0; r < 4; r++) {
            const u16* ga = A + (size_t)(brow + r * 32 + srow) * D_ + (k0 + skk);
            const u16* gb = A + (size_t)(bcol + r * 32 + srow) * D_ + (k0 + skk);
            gload16(ga, &ldsA[r * 2048 + wid * 512]);
            gload16(gb, &ldsB[r * 2048 + wid * 512]);
        }
        __syncthreads();
#pragma unroll
        for (int kk = 0; kk < 64; kk += 32) {
            const int kc = (kk >> 3) + kh;
            const int kswz = ((kc ^ l7) << 3);
            bf16x8 af[4], bfv[4];
#pragma unroll
            for (int m = 0; m < 4; m++)
                af[m] = *(const bf16x8*)&ldsA[(wr * 64 + m * 16 + l15) * 64 + kswz];
#pragma unroll
            for (int n = 0; n < 4; n++)
                bfv[n] = *(const bf16x8*)&ldsB[(wc * 64 + n * 16 + l15) * 64 + kswz];
#pragma unroll
            for (int m = 0; m < 4; m++)
#pragma unroll
                for (int n = 0; n < 4; n++)
                    acc[m][n] = __builtin_amdgcn_mfma_f32_16x16x32_bf16(af[m], bfv[n], acc[m][n], 0, 0, 0);
        }
    }

    const float* mrow = mask + (size_t)(b0 + z) * S_;
    const int nrows = nbatch * S_;

    float rsum[4][4];
#pragma unroll
    for (int m = 0; m < 4; m++)
#pragma unroll
        for (int j = 0; j < 4; j++) rsum[m][j] = 0.f;

#pragma unroll
    for (int m = 0; m < 4; m++)
#pragma unroll
        for (int n = 0; n < 4; n++) {
            int rowb = brow + wr * 64 + m * 16 + (kh << 2);
            int col  = bcol + wc * 64 + n * 16 + l15;
            float madd_c = (1.f - mrow[col]) * -1e9f;
#pragma unroll
            for (int j = 0; j < 4; j++) {
                int row = rowb + j;
                float ev = __expf(acc[m][n][j] * scale + madd_c);
                P[coff + (size_t)row * S_ + col] = f2bf(ev);
                rsum[m][j] += ev;
            }
        }
#pragma unroll
    for (int m = 0; m < 4; m++) {
        int rowl = brow + wr * 64 + m * 16 + (kh << 2);
#pragma unroll
        for (int j = 0; j < 4; j++) {
            float s = rsum[m][j];
            s += __shfl_xor(s, 1);
            s += __shfl_xor(s, 2);
            s += __shfl_xor(s, 4);
            s += __shfl_xor(s, 8);
            if (l15 == 0)
                psum[(size_t)(bx * 2 + wc) * nrows + (size_t)z * S_ + rowl + j] = s;
        }
    }

    if (bx != by) {
#pragma unroll 1
        for (int rnd = 0; rnd < 2; rnd++) {
            __syncthreads();
            if (wc == rnd) {
#pragma unroll
                for (int n = 0; n < 4; n++) {
                    float csum = 0.f;
                    const int mrow_l = n * 16 + l15;
#pragma unroll
                    for (int m = 0; m < 4; m++) {
                        const int lr = wr * 64 + m * 16 + (kh << 2);
                        u16 e2[4];
#pragma unroll
                        for (int j = 0; j < 4; j++) {
                            float madd_r = (1.f - mrow[brow + lr + j]) * -1e9f;
                            float em = __expf(acc[m][n][j] * scale + madd_r);
                            csum += em;
                            e2[j] = f2bf(em);
                        }
                        unsigned* m32 = (unsigned*)&mt[mrow_l * 136 + lr];
                        m32[0] = (unsigned)e2[0] | ((unsigned)e2[1] << 16);
                        m32[1] = (unsigned)e2[2] | ((unsigned)e2[3] << 16);
                    }
                    csum += __shfl_xor(csum, 16);
                    csum += __shfl_xor(csum, 32);
                    if (lane < 16)
                        psum[(size_t)(by * 2 + wr) * nrows + (size_t)z * S_ +
                             bcol + rnd * 64 + n * 16 + lane] = csum;
                }
            }
            __syncthreads();
#pragma unroll 1
            for (int i = tid; i < 64 * 16; i += 256) {
                int rr = i >> 4, c16 = (i & 15) << 3;
                u16 v[8];
#pragma unroll
                for (int q = 0; q < 8; q++) v[q] = mt[rr * 136 + c16 + q];
                *(uint4*)(P + coff + (size_t)(bcol + rnd * 64 + rr) * S_ + brow + c16) = pack8(v);
            }
        }
    }
}

// ---------------- out_w pad+transpose: WTb[64][512] bf16 ----------------
__global__ __launch_bounds__(256) void wtb_kernel(
    const float* __restrict__ W, u16* __restrict__ WTb)
{
    int i = blockIdx.x * 256 + threadIdx.x;
    if (i >= 64 * 512) return;
    int n = i >> 9, k = i & 511;
    WTb[i] = f2bf(n < V_ ? W[k * V_ + n] : 0.f);
}

// ---------------- output projection via MFMA: out = x(bf16) @ W + b ----------
__global__ __launch_bounds__(256) void outproj_mfma(
    const u16* __restrict__ x, const u16* __restrict__ WTb,
    const float* __restrict__ bias, float* __restrict__ out)
{
    __shared__ __align__(16) u16 ldsA[128 * 64];
    __shared__ __align__(16) u16 ldsB[64 * 64];
    __shared__ float obuf[128][34];
    const int brow = blockIdx.x * 128;
    const int tid = threadIdx.x, lane = tid & 63, wid = tid >> 6;
    const int wr = wid >> 1, wc = wid & 1;
    const int l15 = lane & 15, l7 = lane & 7, kh = lane >> 4;
    const int lg = lane >> 3, srow = wid * 8 + lg;
    const int skk = ((lane & 7) ^ lg) << 3;

    f32x4 acc[4][2];
#pragma unroll
    for (int m = 0; m < 4; m++)
#pragma unroll
        for (int n = 0; n < 2; n++) acc[m][n] = 0.0f;

    for (int k0 = 0; k0 < 512; k0 += 64) {
        __syncthreads();
#pragma unroll
        for (int r = 0; r < 2; r++)
            gload16(WTb + (size_t)(r * 32 + srow) * 512 + (k0 + skk),
                    &ldsB[r * 2048 + wid * 512]);
#pragma unroll
        for (int r = 0; r < 4; r++)
            gload16(x + (size_t)(brow + r * 32 + srow) * 512 + (k0 + skk),
                    &ldsA[r * 2048 + wid * 512]);
        __syncthreads();
#pragma unroll
        for (int kk = 0; kk < 64; kk += 32) {
            const int kc = (kk >> 3) + kh;
            const int kswz = ((kc ^ l7) << 3);
            bf16x8 af[4], bfv[2];
#pragma unroll
            for (int m = 0; m < 4; m++)
                af[m] = *(const bf16x8*)&ldsA[(wr * 64 + m * 16 + l15) * 64 + kswz];
#pragma unroll
            for (int n = 0; n < 2; n++)
                bfv[n] = *(const bf16x8*)&ldsB[(wc * 32 + n * 16 + l15) * 64 + kswz];
#pragma unroll
            for (int m = 0; m < 4; m++)
#pragma unroll
                for (int n = 0; n < 2; n++)
                    acc[m][n] = __builtin_amdgcn_mfma_f32_16x16x32_bf16(af[m], bfv[n], acc[m][n], 0, 0, 0);
        }
    }

#pragma unroll
    for (int m = 0; m < 4; m++)
#pragma unroll
        for (int n = 0; n < 2; n++) {
            int rowl = wr * 64 + m * 16 + ((lane >> 4) << 2);
            int col  = wc * 32 + n * 16 + l15;
            if (col < V_) {
#pragma unroll
                for (int j = 0; j < 4; j++)
                    obuf[rowl + j][col] = acc[m][n][j] + bias[col];
            }
        }
    __syncthreads();
    float* ob = out + (size_t)brow * V_;
#pragma unroll 1
    for (int i = tid; i < 128 * V_; i += 256)
        ob[i] = obuf[i / V_][i % V_];
}

extern "C" void kernel_launch(void* const* d_in, const int* in_sizes, int n_in,
                              void* d_out, int out_size, void* d_ws, size_t ws_size,
                              hipStream_t stream)
{
    const int*   input_ids = (const int*)d_in[0];
    const int*   comb      = (const int*)d_in[1];
    const float* amask     = (const float*)d_in[2];
    const float* tok       = (const float*)d_in[3];
    const float* pos       = (const float*)d_in[4];
    const float* attre     = (const float*)d_in[5];
    const float* ln_w      = (const float*)d_in[6];
    const float* ln_b      = (const float*)d_in[7];
    const float* w1        = (const float*)d_in[8];
    const float* b1        = (const float*)d_in[9];
    const float* w2        = (const float*)d_in[10];
    const float* b2        = (const float*)d_in[11];
    const float* out_w     = (const float*)d_in[12];
    const float* out_b     = (const float*)d_in[13];
    float* out = (float*)d_out;
    (void)in_sizes; (void)n_in; (void)out_size;

    // ---- adaptive workspace tiers (ws_size-aware; deterministic) ----
    int NB_A, RC;
    if      (ws_size >= 300000000ULL) { NB_A = 16; RC = 32768; }
    else if (ws_size >= 180000000ULL) { NB_A = 8;  RC = 16384; }
    else if (ws_size >= 120000000ULL) { NB_A = 4;  RC = 8192;  }
    else                              { NB_A = 2;  RC = 4096;  }
    const int HR = NB_A * S_;

    unsigned char* ws = (unsigned char*)d_ws;
    size_t off = 0;
    auto carve = [&](size_t bytes) {
        void* p = ws + off;
        off += (bytes + 255) & ~(size_t)255;
        return p;
    };
    u16* x      = (u16*)carve((size_t)B_ * S_ * D_ * 2);          // bf16 residual
    u16* w1t    = (u16*)carve((size_t)L_ * D_ * FF_ * 2);
    u16* w2t    = (u16*)carve((size_t)L_ * D_ * FF_ * 2);
    u16* h      = (u16*)carve((size_t)HR * D_ * 2);
    u16* hT     = (u16*)carve((size_t)NB_A * S_ * D_ * 2);
    float* psum = (float*)carve((size_t)NB_A * S_ * 32 * 4);
    u16* WTb    = (u16*)carve((size_t)64 * 512 * 2);
    size_t scP_bytes  = (size_t)NB_A * S_ * S_ * 2;
    size_t tbuf_bytes = (size_t)RC * FF_ * 2;
    void* un = carve(scP_bytes > tbuf_bytes ? scP_bytes : tbuf_bytes);
    u16* scP  = (u16*)un;
    u16* tbuf = (u16*)un;

    const float scl = 1.0f / sqrtf((float)D_);
    const int nG = B_ / NB_A;
    const int nC = (B_ * S_) / RC;

    embed_kernel<<<(B_ * S_ * (D_ / 8)) / 256, 256, 0, stream>>>(input_ids, comb, tok, pos, attre, x);
    transpose64<<<dim3(FF_ / 64, D_ / 64, L_), dim3(32, 8), 0, stream>>>(
        w1, w1t, D_, FF_, (size_t)D_ * FF_, (size_t)FF_ * D_);
    transpose64<<<dim3(D_ / 64, FF_ / 64, L_), dim3(32, 8), 0, stream>>>(
        w2, w2t, FF_, D_, (size_t)FF_ * D_, (size_t)D_ * FF_);
    wtb_kernel<<<128, 256, 0, stream>>>(out_w, WTb);

    for (int l = 0; l < L_; l++) {
        const float* lw = ln_w + l * D_;
        const float* lb = ln_b + l * D_;

        for (int g = 0; g < nG; g++) {
            u16* xg = x + (size_t)g * NB_A * S_ * D_;
            lnT_kernel<<<(NB_A * S_) / 64, 1024, 0, stream>>>(xg, h, hT, lw, lb);
            gemm_sc<<<dim3(136, 1, NB_A), 256, 0, stream>>>(
                h, scP, amask, g * NB_A, scl, psum, NB_A);
            gemm_nt<E_PV><<<dim3(D_ / 128, S_ / 128, NB_A), 256, 0, stream>>>(
                scP, (size_t)S_ * S_, S_,
                hT, (size_t)S_ * D_, S_,
                xg, (size_t)S_ * D_, D_,
                S_, xg, (size_t)S_ * D_, nullptr, psum, NB_A * S_);
        }

        for (int c = 0; c < nC; c++) {
            size_t roff = (size_t)c * RC;
            ln_kernel<<<RC / 4, 256, 0, stream>>>(x + roff * D_, h, lw, lb, RC);
            gemm_nt<E_GELU><<<dim3(FF_ / 128, RC / 128, 1), 256, 0, stream>>>(
                h, 0, D_,
                w1t + (size_t)l * FF_ * D_, 0, D_,
                tbuf, 0, FF_,
                D_, nullptr, 0, b1 + l * FF_, nullptr, 0);
            gemm_nt<E_FF2><<<dim3(D_ / 128, RC / 128, 1), 256, 0, stream>>>(
                tbuf, 0, FF_,
                w2t + (size_t)l * D_ * FF_, 0, FF_,
                x + roff * D_, 0, D_,
                FF_, x + roff * D_, 0, b2 + l * D_, nullptr, 0);
        }
    }

    outproj_mfma<<<(B_ * S_) / 128, 256, 0, stream>>>(x, WTb, out_b, out);
}